// Round 5
// baseline (927.806 us; speedup 1.0000x reference)
//
#include <hip/hip_runtime.h>
#include <hip/hip_bf16.h>
#include <cstddef>

#define BATCH 64
#define NK    2048
#define HID   1024
#define EMB   512
#define KEY   512
#define VOCAB 50257

typedef __attribute__((ext_vector_type(8))) short bf16x8;
typedef __attribute__((ext_vector_type(4))) short bf16x4;
typedef __attribute__((ext_vector_type(4))) float f32x4;

__device__ __forceinline__ short f2bf(float f) {
    unsigned u = __builtin_bit_cast(unsigned, f);
    unsigned r = (u + 0x7FFFu + ((u >> 16) & 1u)) >> 16;
    return (short)r;
}

#define GLOAD_LDS16(g, l)                                                  \
    __builtin_amdgcn_global_load_lds(                                      \
        (const __attribute__((address_space(1))) void*)(g),                \
        (__attribute__((address_space(3))) void*)(l), 16, 0, 0)

// ---------------------------------------------------------------------------
// Wk (512 k x 1024 n) f32  ->  WkT (1024 n x 512 k) bf16
// ---------------------------------------------------------------------------
__global__ void wkt_kernel(const float* __restrict__ Wk, short* __restrict__ wkT) {
    __shared__ float t[32][33];
    int k0 = blockIdx.x << 5, n0 = blockIdx.y << 5;
    int tx = threadIdx.x, ty = threadIdx.y; // (32,8)
#pragma unroll
    for (int i = 0; i < 4; ++i)
        t[ty + i * 8][tx] = Wk[(size_t)(k0 + ty + i * 8) * 1024 + n0 + tx];
    __syncthreads();
#pragma unroll
    for (int i = 0; i < 4; ++i)
        wkT[(size_t)(n0 + ty + i * 8) * 512 + k0 + tx] = f2bf(t[tx][ty + i * 8]);
}

// ---------------------------------------------------------------------------
// Small fp32 GEMM: C(64 x N) += A(64 x K=1024) * B,  B either [K][N] or [N][K]
// grid (N/64, 8) k-split, block 256. C pre-zeroed (atomic accumulate).
// ---------------------------------------------------------------------------
template <int TB>
__global__ __launch_bounds__(256) void sgemm64(const float* __restrict__ A,
                                               const float* __restrict__ B,
                                               float* __restrict__ C, int N, int K) {
    __shared__ float As2[32][68];
    __shared__ float Bs2[32][68];
    int tid = threadIdx.x;
    int n0 = blockIdx.x << 6;
    int kb = blockIdx.y << 7; // K/8 = 128 per split
    int tn = (tid & 15) << 2, tm = (tid >> 4) << 2;
    float acc[4][4] = {};
    for (int kc = 0; kc < 128; kc += 32) {
        int kk = kb + kc;
#pragma unroll
        for (int i = 0; i < 8; ++i) {
            int idx = i * 256 + tid;
            int ml = idx >> 5, kl = idx & 31;
            As2[kl][ml] = A[(size_t)ml * K + kk + kl];
        }
        if (TB) {
#pragma unroll
            for (int i = 0; i < 8; ++i) {
                int idx = i * 256 + tid;
                int nl = idx >> 5, kl = idx & 31;
                Bs2[kl][nl] = B[(size_t)(n0 + nl) * K + kk + kl];
            }
        } else {
#pragma unroll
            for (int i = 0; i < 8; ++i) {
                int idx = i * 256 + tid;
                int kl = idx >> 6, nl = idx & 63;
                Bs2[kl][nl] = B[(size_t)(kk + kl) * N + n0 + nl];
            }
        }
        __syncthreads();
#pragma unroll
        for (int k = 0; k < 32; ++k) {
            float a0 = As2[k][tm], a1 = As2[k][tm + 1], a2 = As2[k][tm + 2], a3 = As2[k][tm + 3];
            float b0 = Bs2[k][tn], b1 = Bs2[k][tn + 1], b2 = Bs2[k][tn + 2], b3 = Bs2[k][tn + 3];
            acc[0][0] += a0 * b0; acc[0][1] += a0 * b1; acc[0][2] += a0 * b2; acc[0][3] += a0 * b3;
            acc[1][0] += a1 * b0; acc[1][1] += a1 * b1; acc[1][2] += a1 * b2; acc[1][3] += a1 * b3;
            acc[2][0] += a2 * b0; acc[2][1] += a2 * b1; acc[2][2] += a2 * b2; acc[2][3] += a2 * b3;
            acc[3][0] += a3 * b0; acc[3][1] += a3 * b1; acc[3][2] += a3 * b2; acc[3][3] += a3 * b3;
        }
        __syncthreads();
    }
#pragma unroll
    for (int i = 0; i < 4; ++i)
#pragma unroll
        for (int j = 0; j < 4; ++j)
            atomicAdd(&C[(size_t)(tm + i) * N + n0 + tn + j], acc[i][j]);
}

// ---------------------------------------------------------------------------
// scores v4: v3's double-buffered pipeline, but the in-loop barrier is now
// raw s_barrier with COUNTED vmcnt (T4): per iter, issue order is
// glds B(t+1) x2 (old) then A f32 prefetch x2 (young, unconditional so the
// youngest-2 invariant holds on every iteration incl. 30/31).
//   s_waitcnt vmcnt(2) lgkmcnt(0)  -> drains glds + all LDS ops, but lets
//   the 2 A-prefetch loads ride across the barrier (HBM latency hidden).
// __syncthreads (vmcnt(0) drain) re-exposed full HBM latency every iter.
// ---------------------------------------------------------------------------
__global__ __launch_bounds__(512, 4) void scores_kernel(const float* __restrict__ ann,
                                                        const short* __restrict__ wkT,
                                                        const float* __restrict__ qc,
                                                        const float* __restrict__ bk,
                                                        const float* __restrict__ vat,
                                                        float* __restrict__ scores2) {
    __shared__ __align__(16) short As[2 * 128 * 32];
    __shared__ __align__(16) short Bs[2 * 256 * 32];
    __shared__ float red[128][4];

    int bx = blockIdx.x;
    int rb = ((bx >> 4) << 3) | (bx & 7);
    int hs = (bx >> 3) & 1;
    int row0 = rb << 7;
    int b = row0 >> 11;
    int tid = threadIdx.x, lane = tid & 63, wv = tid >> 6;
    int wm = wv & 1, wn = wv >> 1;       // 2 m-waves x 4 n-waves
    int q = lane >> 4, c = lane & 15;

    // staging lane roles
    int sm = tid >> 2;                    // A row 0..127 / B row-in-128 chunk
    int sq = tid & 3;                     // logical k-quarter (A) / phys slot (B)
    int sxor = (tid >> 3) & 3;            // (row>>1)&3 for both A and B lanes
    int aphys = sq ^ sxor;                // A: physical slot
    int bqlog = sq ^ sxor;                // B: logical quarter for phys slot sq
    int swz = (q ^ ((c >> 1) & 3)) << 3;  // frag-read swizzled short-offset

    const float* qcb = qc + b * 1024;
    const float* abase = ann + (size_t)(row0 + sm) * 512 + sq * 8;
    const short* bbase = wkT + (size_t)(hs * 512 + sm) * 512 + bqlog * 8;

    float pscore[4][4] = {};
    f32x4 acc[4][4];
#pragma unroll
    for (int mi = 0; mi < 4; ++mi)
#pragma unroll
        for (int ni = 0; ni < 4; ++ni)
            acc[mi][ni] = (f32x4){0.f, 0.f, 0.f, 0.f};

    // ---- prologue: tile0 into buf0, A-regs for tile1 in flight ----
    float4 pa0 = *(const float4*)abase;
    float4 pa1 = *(const float4*)(abase + 4);
    GLOAD_LDS16(bbase, Bs + (wv << 9));
    GLOAD_LDS16(bbase + 128 * 512, Bs + 4096 + (wv << 9));
    {
        bf16x8 ap;
        ap[0] = f2bf(pa0.x); ap[1] = f2bf(pa0.y); ap[2] = f2bf(pa0.z); ap[3] = f2bf(pa0.w);
        ap[4] = f2bf(pa1.x); ap[5] = f2bf(pa1.y); ap[6] = f2bf(pa1.z); ap[7] = f2bf(pa1.w);
        *(bf16x8*)(As + sm * 32 + aphys * 8) = ap;
    }
    pa0 = *(const float4*)(abase + 32);
    pa1 = *(const float4*)(abase + 36);
    __syncthreads();

    // ---- main pipeline: t = nc*16 + ks ----
#pragma unroll 2
    for (int t = 0; t < 32; ++t) {
        short* Asc = As + (t & 1) * 4096;
        short* Bsc = Bs + ((t & 1) << 13);
        short* Asn = As + ((t & 1) ^ 1) * 4096;
        short* Bsn = Bs + (((t & 1) ^ 1) << 13);
        if (t < 31) {
            int t1 = t + 1;
            const short* bs = bbase + (size_t)((t1 >> 4) * (256 * 512)) + ((t1 & 15) << 5);
            GLOAD_LDS16(bs, Bsn + (wv << 9));
            GLOAD_LDS16(bs + 128 * 512, Bsn + 4096 + (wv << 9));
            bf16x8 ap;
            ap[0] = f2bf(pa0.x); ap[1] = f2bf(pa0.y); ap[2] = f2bf(pa0.z); ap[3] = f2bf(pa0.w);
            ap[4] = f2bf(pa1.x); ap[5] = f2bf(pa1.y); ap[6] = f2bf(pa1.z); ap[7] = f2bf(pa1.w);
            *(bf16x8*)(Asn + sm * 32 + aphys * 8) = ap;
        }
        // A prefetch for t+2: UNCONDITIONAL (index wraps mod 16) so the two
        // youngest VMEM ops at the barrier are always these — vmcnt(2)'s
        // drain-glds invariant holds on iters 30/31 too (guarded version
        // would race: t=30's barrier would leave its glds undrained).
        {
            const float* as = abase + (((t + 2) & 15) << 5);
            pa0 = *(const float4*)as;
            pa1 = *(const float4*)(as + 4);
        }
        // ---- fragments + MFMA from front buffer ----
        bf16x8 af[4];
#pragma unroll
        for (int mi = 0; mi < 4; ++mi)
            af[mi] = *(const bf16x8*)(Asc + (wm * 64 + mi * 16 + c) * 32 + swz);
#pragma unroll
        for (int ni = 0; ni < 4; ++ni) {
            bf16x8 bfr = *(const bf16x8*)(Bsc + (wn * 64 + ni * 16 + c) * 32 + swz);
#pragma unroll
            for (int mi = 0; mi < 4; ++mi)
                acc[mi][ni] = __builtin_amdgcn_mfma_f32_16x16x32_bf16(af[mi], bfr, acc[mi][ni], 0, 0, 0);
        }
        // ---- epilogue per 256-h chunk: tanh(S+qc+bk)*v, accumulate ----
        if ((t & 15) == 15) {
            int hbase = hs * 512 + (t >> 4) * 256 + wn * 64;
#pragma unroll
            for (int ni = 0; ni < 4; ++ni) {
                int h = hbase + ni * 16 + c;
                float qv = qcb[h] + bk[h];
                float vv = vat[h];
#pragma unroll
                for (int mi = 0; mi < 4; ++mi) {
#pragma unroll
                    for (int rg = 0; rg < 4; ++rg) {
                        float xv = acc[mi][ni][rg] + qv;
                        float e = __expf(2.0f * xv);
                        pscore[mi][rg] += (1.0f - 2.0f / (e + 1.0f)) * vv;
                        acc[mi][ni][rg] = 0.f;
                    }
                }
            }
        }
        // ---- counted-vmcnt barrier (T4): keep A-prefetch in flight ----
        __builtin_amdgcn_sched_barrier(0);
        asm volatile("s_waitcnt vmcnt(2) lgkmcnt(0)" ::: "memory");
        __builtin_amdgcn_s_barrier();
        __builtin_amdgcn_sched_barrier(0);
    }

    // ---- cross-lane + cross-wave reduction, direct store (no atomics) ----
#pragma unroll
    for (int mi = 0; mi < 4; ++mi)
#pragma unroll
        for (int rg = 0; rg < 4; ++rg) {
            float p = pscore[mi][rg];
            p += __shfl_xor(p, 1, 16);
            p += __shfl_xor(p, 2, 16);
            p += __shfl_xor(p, 4, 16);
            p += __shfl_xor(p, 8, 16);
            if (c == 0) red[wm * 64 + mi * 16 + q * 4 + rg][wn] = p;
        }
    __syncthreads();
    if (tid < 128)
        scores2[(size_t)hs * 131072 + row0 + tid] =
            red[tid][0] + red[tid][1] + red[tid][2] + red[tid][3];
}

// ---------------------------------------------------------------------------
// softmax over NK=2048 per batch row, summing the two h-half planes
// ---------------------------------------------------------------------------
__global__ __launch_bounds__(256) void softmax_kernel(const float* __restrict__ scores2,
                                                      float* __restrict__ a_out) {
    __shared__ float red[4];
    int b = blockIdx.x, tid = threadIdx.x;
    const float* s0 = scores2 + b * 2048;
    const float* s1 = s0 + 131072;
    float loc[8];
    float vmax = -1e30f;
#pragma unroll
    for (int i = 0; i < 8; ++i) {
        loc[i] = s0[tid + i * 256] + s1[tid + i * 256];
        vmax = fmaxf(vmax, loc[i]);
    }
#pragma unroll
    for (int m = 32; m; m >>= 1) vmax = fmaxf(vmax, __shfl_xor(vmax, m));
    if ((tid & 63) == 0) red[tid >> 6] = vmax;
    __syncthreads();
    vmax = fmaxf(fmaxf(red[0], red[1]), fmaxf(red[2], red[3]));
    float sum = 0.f;
#pragma unroll
    for (int i = 0; i < 8; ++i) { loc[i] = __expf(loc[i] - vmax); sum += loc[i]; }
#pragma unroll
    for (int m = 32; m; m >>= 1) sum += __shfl_xor(sum, m);
    __syncthreads();
    if ((tid & 63) == 0) red[tid >> 6] = sum;
    __syncthreads();
    sum = red[0] + red[1] + red[2] + red[3];
    float inv = 1.0f / sum;
#pragma unroll
    for (int i = 0; i < 8; ++i) a_out[b * 2048 + tid + i * 256] = loc[i] * inv;
}

// ---------------------------------------------------------------------------
// context partials: part[nchunk][b][k] = sum over 128 n (no atomics)
// ---------------------------------------------------------------------------
__global__ __launch_bounds__(256) void context_kernel(const float* __restrict__ a_out,
                                                      const float* __restrict__ ann,
                                                      float* __restrict__ ctxpart) {
    int b = blockIdx.y, nch = blockIdx.x, n0 = nch << 7;
    int k = threadIdx.x << 1;
    const float* base = ann + ((size_t)b * 2048 + n0) * 512 + k;
    const float* av = a_out + b * 2048 + n0;
    float ax = 0.f, ay = 0.f;
    for (int n = 0; n < 128; ++n) {
        float w = av[n];
        float2 v = *(const float2*)(base + (size_t)n * 512);
        ax += w * v.x;
        ay += w * v.y;
    }
    float* dst = ctxpart + ((size_t)nch * 64 + b) * 512 + k;
    dst[0] = ax;
    dst[1] = ay;
}

// ---------------------------------------------------------------------------
// x = concat(emb_table[ids], sum of 16 context partials)  (64 x 1024)
// ---------------------------------------------------------------------------
__global__ void x_kernel(const int* __restrict__ ids, const float* __restrict__ emb,
                         const float* __restrict__ ctxpart, float* __restrict__ x) {
    int idx = blockIdx.x * 256 + threadIdx.x;
    int b = idx >> 10, k = idx & 1023;
    if (k < 512) {
        x[idx] = emb[(size_t)ids[b] * 512 + k];
    } else {
        int kk = k - 512;
        float s = 0.f;
#pragma unroll
        for (int i = 0; i < 16; ++i) s += ctxpart[((size_t)i * 64 + b) * 512 + kk];
        x[idx] = s;
    }
}

// ---------------------------------------------------------------------------
// GRU cell elementwise -> o (f32, d_out) and h (bf16, ws)
// ---------------------------------------------------------------------------
__global__ void gru_kernel(const float* __restrict__ gi, const float* __restrict__ gh,
                           const float* __restrict__ bih, const float* __restrict__ bhh,
                           const float* __restrict__ hidden, float* __restrict__ o_out,
                           short* __restrict__ hbf) {
    int idx = blockIdx.x * 256 + threadIdx.x;
    int b = idx >> 10, h = idx & 1023;
    const float* gib = gi + b * 3072;
    const float* ghb = gh + b * 3072;
    float ir = gib[h] + bih[h],               hr = ghb[h] + bhh[h];
    float iz = gib[1024 + h] + bih[1024 + h], hz = ghb[1024 + h] + bhh[1024 + h];
    float in = gib[2048 + h] + bih[2048 + h], hn = ghb[2048 + h] + bhh[2048 + h];
    float r = 1.0f / (1.0f + __expf(-(ir + hr)));
    float z = 1.0f / (1.0f + __expf(-(iz + hz)));
    float nn = tanhf(in + r * hn);
    float hq = hidden[idx];
    float hnew = (1.0f - z) * nn + z * hq;
    o_out[idx] = hnew;
    hbf[idx] = f2bf(hnew);
}

// ---------------------------------------------------------------------------
// logits = h(64x1024) @ W_out^T + b_out  (MFMA, B converted inline)
// ---------------------------------------------------------------------------
__global__ __launch_bounds__(256) void logits_kernel(const short* __restrict__ hbf,
                                                     const float* __restrict__ Wout,
                                                     const float* __restrict__ bout,
                                                     float* __restrict__ logits) {
    int tid = threadIdx.x, lane = tid & 63, wv = tid >> 6;
    int q = lane >> 4, c = lane & 15;
    int v = blockIdx.x * 64 + wv * 16 + c;
    int vc = v < VOCAB ? v : (VOCAB - 1);
    const float* wrow = Wout + (size_t)vc * 1024;
    f32x4 acc[4];
#pragma unroll
    for (int mi = 0; mi < 4; ++mi) acc[mi] = (f32x4){0.f, 0.f, 0.f, 0.f};
#pragma unroll 4
    for (int ks = 0; ks < 32; ++ks) {
        int k0 = ks * 32 + q * 8;
        float4 w0 = *(const float4*)(wrow + k0);
        float4 w1 = *(const float4*)(wrow + k0 + 4);
        bf16x8 bfr;
        bfr[0] = f2bf(w0.x); bfr[1] = f2bf(w0.y); bfr[2] = f2bf(w0.z); bfr[3] = f2bf(w0.w);
        bfr[4] = f2bf(w1.x); bfr[5] = f2bf(w1.y); bfr[6] = f2bf(w1.z); bfr[7] = f2bf(w1.w);
#pragma unroll
        for (int mi = 0; mi < 4; ++mi) {
            bf16x8 af = *(const bf16x8*)(hbf + (size_t)(mi * 16 + c) * 1024 + k0);
            acc[mi] = __builtin_amdgcn_mfma_f32_16x16x32_bf16(af, bfr, acc[mi], 0, 0, 0);
        }
    }
    if (v < VOCAB) {
        float bo = bout[v];
#pragma unroll
        for (int mi = 0; mi < 4; ++mi)
#pragma unroll
            for (int rg = 0; rg < 4; ++rg) {
                int row = mi * 16 + q * 4 + rg;
                logits[(size_t)row * VOCAB + v] = acc[mi][rg] + bo;
            }
    }
}

// ---------------------------------------------------------------------------
// in-place log_softmax over VOCAB per row (64 rows)
// 1024 threads/block: only 64 blocks exist (one per row), so per-CU wave
// count is the only memory-parallelism lever — 256 thr was 1 wave/SIMD.
// ---------------------------------------------------------------------------
__global__ __launch_bounds__(1024) void logsoftmax_kernel(float* __restrict__ logp) {
    __shared__ float red[16];
    int b = blockIdx.x, tid = threadIdx.x;
    float* row = logp + (size_t)b * VOCAB;
    float vmax = -1e30f;
    for (int i = tid; i < VOCAB; i += 1024) vmax = fmaxf(vmax, row[i]);
#pragma unroll
    for (int m = 32; m; m >>= 1) vmax = fmaxf(vmax, __shfl_xor(vmax, m));
    if ((tid & 63) == 0) red[tid >> 6] = vmax;
    __syncthreads();
    float m0 = red[0];
#pragma unroll
    for (int i = 1; i < 16; ++i) m0 = fmaxf(m0, red[i]);
    vmax = m0;
    float sum = 0.f;
    for (int i = tid; i < VOCAB; i += 1024) sum += __expf(row[i] - vmax);
#pragma unroll
    for (int m = 32; m; m >>= 1) sum += __shfl_xor(sum, m);
    __syncthreads();
    if ((tid & 63) == 0) red[tid >> 6] = sum;
    __syncthreads();
    float s0 = 0.f;
#pragma unroll
    for (int i = 0; i < 16; ++i) s0 += red[i];
    float lse = vmax + logf(s0);
    for (int i = tid; i < VOCAB; i += 1024) row[i] = row[i] - lse;
}

// ---------------------------------------------------------------------------
extern "C" void kernel_launch(void* const* d_in, const int* in_sizes, int n_in,
                              void* d_out, int out_size, void* d_ws, size_t ws_size,
                              hipStream_t stream) {
    const int* ids      = (const int*)d_in[0];
    const float* hidden = (const float*)d_in[1];
    const float* ann    = (const float*)d_in[2];
    const float* embT   = (const float*)d_in[3];
    const float* Wk     = (const float*)d_in[4];
    const float* Wq     = (const float*)d_in[5];
    const float* bk     = (const float*)d_in[6];
    const float* vat    = (const float*)d_in[7];
    const float* Wih    = (const float*)d_in[8];
    const float* Whh    = (const float*)d_in[9];
    const float* bih    = (const float*)d_in[10];
    const float* bhh    = (const float*)d_in[11];
    const float* Wout   = (const float*)d_in[12];
    const float* bout   = (const float*)d_in[13];

    float* out   = (float*)d_out;
    float* logp  = out;                         // 64*50257 (logits in-place)
    float* o_out = out + (size_t)BATCH * VOCAB; // 64*1024
    float* a_out = o_out + BATCH * HID;         // 64*2048

    // ws layout (floats). scores2 (262144) and ctxpart (524288) overlay:
    // softmax consumes scores2 before context writes ctxpart.
    float* shared0 = (float*)d_ws;
    float* scores2 = shared0;
    float* ctxpart = shared0;
    float* qc      = shared0 + 524288;          // 65536
    float* gh      = qc + 65536;                // 196608
    float* gi      = gh + 196608;               // 196608
    float* x       = gi + 196608;               // 65536
    short* wkT     = (short*)(x + 65536);       // 524288 shorts
    short* hbf     = wkT + 524288;              // 65536 shorts

    // zero atomic-accumulated regions qc|gh|gi (contiguous, 458752 floats)
    hipMemsetAsync(qc, 0, (size_t)458752 * sizeof(float), stream);

    wkt_kernel<<<dim3(16, 32), dim3(32, 8), 0, stream>>>(Wk, wkT);
    sgemm64<0><<<dim3(16, 8), 256, 0, stream>>>(hidden, Wq, qc, 1024, 1024);
    sgemm64<1><<<dim3(48, 8), 256, 0, stream>>>(hidden, Whh, gh, 3072, 1024);
    scores_kernel<<<2048, 512, 0, stream>>>(ann, wkT, qc, bk, vat, scores2);
    softmax_kernel<<<64, 256, 0, stream>>>(scores2, a_out);
    context_kernel<<<dim3(16, 64), 256, 0, stream>>>(a_out, ann, ctxpart);
    x_kernel<<<256, 256, 0, stream>>>(ids, embT, ctxpart, x);
    sgemm64<1><<<dim3(48, 8), 256, 0, stream>>>(x, Wih, gi, 3072, 1024);
    gru_kernel<<<256, 256, 0, stream>>>(gi, gh, bih, bhh, hidden, o_out, hbf);
    logits_kernel<<<(VOCAB + 63) / 64, 256, 0, stream>>>(hbf, Wout, bout, logp);
    logsoftmax_kernel<<<64, 1024, 0, stream>>>(logp);
}

// Round 6
// 907.683 us; speedup vs baseline: 1.0222x; 1.0222x over previous
//
#include <hip/hip_runtime.h>
#include <hip/hip_bf16.h>
#include <cstddef>

#define BATCH 64
#define NK    2048
#define HID   1024
#define EMB   512
#define KEY   512
#define VOCAB 50257

typedef __attribute__((ext_vector_type(8))) short bf16x8;
typedef __attribute__((ext_vector_type(4))) short bf16x4;
typedef __attribute__((ext_vector_type(4))) float f32x4;

__device__ __forceinline__ short f2bf(float f) {
    unsigned u = __builtin_bit_cast(unsigned, f);
    unsigned r = (u + 0x7FFFu + ((u >> 16) & 1u)) >> 16;
    return (short)r;
}

#define GLOAD_LDS16(g, l)                                                  \
    __builtin_amdgcn_global_load_lds(                                      \
        (const __attribute__((address_space(1))) void*)(g),                \
        (__attribute__((address_space(3))) void*)(l), 16, 0, 0)

// ---------------------------------------------------------------------------
// Wk (512 k x 1024 n) f32  ->  WkT (1024 n x 512 k) bf16
// ---------------------------------------------------------------------------
__global__ void wkt_kernel(const float* __restrict__ Wk, short* __restrict__ wkT) {
    __shared__ float t[32][33];
    int k0 = blockIdx.x << 5, n0 = blockIdx.y << 5;
    int tx = threadIdx.x, ty = threadIdx.y; // (32,8)
#pragma unroll
    for (int i = 0; i < 4; ++i)
        t[ty + i * 8][tx] = Wk[(size_t)(k0 + ty + i * 8) * 1024 + n0 + tx];
    __syncthreads();
#pragma unroll
    for (int i = 0; i < 4; ++i)
        wkT[(size_t)(n0 + ty + i * 8) * 512 + k0 + tx] = f2bf(t[tx][ty + i * 8]);
}

// ---------------------------------------------------------------------------
// Small fp32 GEMM: C(64 x N) += A(64 x K=1024) * B,  B either [K][N] or [N][K]
// grid (N/64, 8) k-split, block 256. C pre-zeroed (atomic accumulate).
// ---------------------------------------------------------------------------
template <int TB>
__global__ __launch_bounds__(256) void sgemm64(const float* __restrict__ A,
                                               const float* __restrict__ B,
                                               float* __restrict__ C, int N, int K) {
    __shared__ float As2[32][68];
    __shared__ float Bs2[32][68];
    int tid = threadIdx.x;
    int n0 = blockIdx.x << 6;
    int kb = blockIdx.y << 7; // K/8 = 128 per split
    int tn = (tid & 15) << 2, tm = (tid >> 4) << 2;
    float acc[4][4] = {};
    for (int kc = 0; kc < 128; kc += 32) {
        int kk = kb + kc;
#pragma unroll
        for (int i = 0; i < 8; ++i) {
            int idx = i * 256 + tid;
            int ml = idx >> 5, kl = idx & 31;
            As2[kl][ml] = A[(size_t)ml * K + kk + kl];
        }
        if (TB) {
#pragma unroll
            for (int i = 0; i < 8; ++i) {
                int idx = i * 256 + tid;
                int nl = idx >> 5, kl = idx & 31;
                Bs2[kl][nl] = B[(size_t)(n0 + nl) * K + kk + kl];
            }
        } else {
#pragma unroll
            for (int i = 0; i < 8; ++i) {
                int idx = i * 256 + tid;
                int kl = idx >> 6, nl = idx & 63;
                Bs2[kl][nl] = B[(size_t)(kk + kl) * N + n0 + nl];
            }
        }
        __syncthreads();
#pragma unroll
        for (int k = 0; k < 32; ++k) {
            float a0 = As2[k][tm], a1 = As2[k][tm + 1], a2 = As2[k][tm + 2], a3 = As2[k][tm + 3];
            float b0 = Bs2[k][tn], b1 = Bs2[k][tn + 1], b2 = Bs2[k][tn + 2], b3 = Bs2[k][tn + 3];
            acc[0][0] += a0 * b0; acc[0][1] += a0 * b1; acc[0][2] += a0 * b2; acc[0][3] += a0 * b3;
            acc[1][0] += a1 * b0; acc[1][1] += a1 * b1; acc[1][2] += a1 * b2; acc[1][3] += a1 * b3;
            acc[2][0] += a2 * b0; acc[2][1] += a2 * b1; acc[2][2] += a2 * b2; acc[2][3] += a2 * b3;
            acc[3][0] += a3 * b0; acc[3][1] += a3 * b1; acc[3][2] += a3 * b2; acc[3][3] += a3 * b3;
        }
        __syncthreads();
    }
#pragma unroll
    for (int i = 0; i < 4; ++i)
#pragma unroll
        for (int j = 0; j < 4; ++j)
            atomicAdd(&C[(size_t)(tm + i) * N + n0 + tn + j], acc[i][j]);
}

// ---------------------------------------------------------------------------
// scores v3 (PROVEN 271 us, reverted from v4's counted-vmcnt which regressed
// to 288: the glds drain still sat on the critical path and sched_barrier(0)
// pinning blocked the compiler's VALU overlap). Double-buffered single-barrier
// pipeline: iter t stages tile t+1 (glds B + reg->bf16 A), prefetches A-regs
// for t+2, MFMAs tile t, one __syncthreads per tile.
// ---------------------------------------------------------------------------
__global__ __launch_bounds__(512, 4) void scores_kernel(const float* __restrict__ ann,
                                                        const short* __restrict__ wkT,
                                                        const float* __restrict__ qc,
                                                        const float* __restrict__ bk,
                                                        const float* __restrict__ vat,
                                                        float* __restrict__ scores2) {
    __shared__ __align__(16) short As[2 * 128 * 32];
    __shared__ __align__(16) short Bs[2 * 256 * 32];
    __shared__ float red[128][4];

    int bx = blockIdx.x;
    int rb = ((bx >> 4) << 3) | (bx & 7);
    int hs = (bx >> 3) & 1;
    int row0 = rb << 7;
    int b = row0 >> 11;
    int tid = threadIdx.x, lane = tid & 63, wv = tid >> 6;
    int wm = wv & 1, wn = wv >> 1;       // 2 m-waves x 4 n-waves
    int q = lane >> 4, c = lane & 15;

    // staging lane roles
    int sm = tid >> 2;                    // A row 0..127 / B row-in-128 chunk
    int sq = tid & 3;                     // logical k-quarter (A) / phys slot (B)
    int sxor = (tid >> 3) & 3;            // (row>>1)&3 for both A and B lanes
    int aphys = sq ^ sxor;                // A: physical slot
    int bqlog = sq ^ sxor;                // B: logical quarter for phys slot sq
    int swz = (q ^ ((c >> 1) & 3)) << 3;  // frag-read swizzled short-offset

    const float* qcb = qc + b * 1024;
    const float* abase = ann + (size_t)(row0 + sm) * 512 + sq * 8;
    const short* bbase = wkT + (size_t)(hs * 512 + sm) * 512 + bqlog * 8;

    float pscore[4][4] = {};
    f32x4 acc[4][4];
#pragma unroll
    for (int mi = 0; mi < 4; ++mi)
#pragma unroll
        for (int ni = 0; ni < 4; ++ni)
            acc[mi][ni] = (f32x4){0.f, 0.f, 0.f, 0.f};

    // ---- prologue: tile0 into buf0, A-regs for tile1 in flight ----
    float4 pa0 = *(const float4*)abase;
    float4 pa1 = *(const float4*)(abase + 4);
    GLOAD_LDS16(bbase, Bs + (wv << 9));
    GLOAD_LDS16(bbase + 128 * 512, Bs + 4096 + (wv << 9));
    {
        bf16x8 ap;
        ap[0] = f2bf(pa0.x); ap[1] = f2bf(pa0.y); ap[2] = f2bf(pa0.z); ap[3] = f2bf(pa0.w);
        ap[4] = f2bf(pa1.x); ap[5] = f2bf(pa1.y); ap[6] = f2bf(pa1.z); ap[7] = f2bf(pa1.w);
        *(bf16x8*)(As + sm * 32 + aphys * 8) = ap;
    }
    pa0 = *(const float4*)(abase + 32);
    pa1 = *(const float4*)(abase + 36);
    __syncthreads();

    // ---- main pipeline: t = nc*16 + ks ----
#pragma unroll 2
    for (int t = 0; t < 32; ++t) {
        short* Asc = As + (t & 1) * 4096;
        short* Bsc = Bs + ((t & 1) << 13);
        short* Asn = As + ((t & 1) ^ 1) * 4096;
        short* Bsn = Bs + (((t & 1) ^ 1) << 13);
        if (t < 31) {
            int t1 = t + 1;
            const short* bs = bbase + (size_t)((t1 >> 4) * (256 * 512)) + ((t1 & 15) << 5);
            GLOAD_LDS16(bs, Bsn + (wv << 9));
            GLOAD_LDS16(bs + 128 * 512, Bsn + 4096 + (wv << 9));
            bf16x8 ap;
            ap[0] = f2bf(pa0.x); ap[1] = f2bf(pa0.y); ap[2] = f2bf(pa0.z); ap[3] = f2bf(pa0.w);
            ap[4] = f2bf(pa1.x); ap[5] = f2bf(pa1.y); ap[6] = f2bf(pa1.z); ap[7] = f2bf(pa1.w);
            *(bf16x8*)(Asn + sm * 32 + aphys * 8) = ap;
        }
        if (t < 30) {
            const float* as = abase + (((t + 2) & 15) << 5);
            pa0 = *(const float4*)as;
            pa1 = *(const float4*)(as + 4);
        }
        // ---- fragments + MFMA from front buffer ----
        bf16x8 af[4];
#pragma unroll
        for (int mi = 0; mi < 4; ++mi)
            af[mi] = *(const bf16x8*)(Asc + (wm * 64 + mi * 16 + c) * 32 + swz);
#pragma unroll
        for (int ni = 0; ni < 4; ++ni) {
            bf16x8 bfr = *(const bf16x8*)(Bsc + (wn * 64 + ni * 16 + c) * 32 + swz);
#pragma unroll
            for (int mi = 0; mi < 4; ++mi)
                acc[mi][ni] = __builtin_amdgcn_mfma_f32_16x16x32_bf16(af[mi], bfr, acc[mi][ni], 0, 0, 0);
        }
        // ---- epilogue per 256-h chunk: tanh(S+qc+bk)*v, accumulate ----
        if ((t & 15) == 15) {
            int hbase = hs * 512 + (t >> 4) * 256 + wn * 64;
#pragma unroll
            for (int ni = 0; ni < 4; ++ni) {
                int h = hbase + ni * 16 + c;
                float qv = qcb[h] + bk[h];
                float vv = vat[h];
#pragma unroll
                for (int mi = 0; mi < 4; ++mi) {
#pragma unroll
                    for (int rg = 0; rg < 4; ++rg) {
                        float xv = acc[mi][ni][rg] + qv;
                        float e = __expf(2.0f * xv);
                        pscore[mi][rg] += (1.0f - 2.0f / (e + 1.0f)) * vv;
                        acc[mi][ni][rg] = 0.f;
                    }
                }
            }
        }
        __syncthreads();
    }

    // ---- cross-lane + cross-wave reduction, direct store (no atomics) ----
#pragma unroll
    for (int mi = 0; mi < 4; ++mi)
#pragma unroll
        for (int rg = 0; rg < 4; ++rg) {
            float p = pscore[mi][rg];
            p += __shfl_xor(p, 1, 16);
            p += __shfl_xor(p, 2, 16);
            p += __shfl_xor(p, 4, 16);
            p += __shfl_xor(p, 8, 16);
            if (c == 0) red[wm * 64 + mi * 16 + q * 4 + rg][wn] = p;
        }
    __syncthreads();
    if (tid < 128)
        scores2[(size_t)hs * 131072 + row0 + tid] =
            red[tid][0] + red[tid][1] + red[tid][2] + red[tid][3];
}

// ---------------------------------------------------------------------------
// softmax over NK=2048 per batch row, summing the two h-half planes
// ---------------------------------------------------------------------------
__global__ __launch_bounds__(256) void softmax_kernel(const float* __restrict__ scores2,
                                                      float* __restrict__ a_out) {
    __shared__ float red[4];
    int b = blockIdx.x, tid = threadIdx.x;
    const float* s0 = scores2 + b * 2048;
    const float* s1 = s0 + 131072;
    float loc[8];
    float vmax = -1e30f;
#pragma unroll
    for (int i = 0; i < 8; ++i) {
        loc[i] = s0[tid + i * 256] + s1[tid + i * 256];
        vmax = fmaxf(vmax, loc[i]);
    }
#pragma unroll
    for (int m = 32; m; m >>= 1) vmax = fmaxf(vmax, __shfl_xor(vmax, m));
    if ((tid & 63) == 0) red[tid >> 6] = vmax;
    __syncthreads();
    vmax = fmaxf(fmaxf(red[0], red[1]), fmaxf(red[2], red[3]));
    float sum = 0.f;
#pragma unroll
    for (int i = 0; i < 8; ++i) { loc[i] = __expf(loc[i] - vmax); sum += loc[i]; }
#pragma unroll
    for (int m = 32; m; m >>= 1) sum += __shfl_xor(sum, m);
    __syncthreads();
    if ((tid & 63) == 0) red[tid >> 6] = sum;
    __syncthreads();
    sum = red[0] + red[1] + red[2] + red[3];
    float inv = 1.0f / sum;
#pragma unroll
    for (int i = 0; i < 8; ++i) a_out[b * 2048 + tid + i * 256] = loc[i] * inv;
}

// ---------------------------------------------------------------------------
// context partials: part[nchunk][b][k] = sum over 128 n (no atomics)
// unroll 4: keep >=4 independent float2 loads in flight (serial-latency fix)
// ---------------------------------------------------------------------------
__global__ __launch_bounds__(256) void context_kernel(const float* __restrict__ a_out,
                                                      const float* __restrict__ ann,
                                                      float* __restrict__ ctxpart) {
    int b = blockIdx.y, nch = blockIdx.x, n0 = nch << 7;
    int k = threadIdx.x << 1;
    const float* base = ann + ((size_t)b * 2048 + n0) * 512 + k;
    const float* av = a_out + b * 2048 + n0;
    float ax = 0.f, ay = 0.f;
#pragma unroll 4
    for (int n = 0; n < 128; ++n) {
        float w = av[n];
        float2 v = *(const float2*)(base + (size_t)n * 512);
        ax += w * v.x;
        ay += w * v.y;
    }
    float* dst = ctxpart + ((size_t)nch * 64 + b) * 512 + k;
    dst[0] = ax;
    dst[1] = ay;
}

// ---------------------------------------------------------------------------
// x = concat(emb_table[ids], sum of 16 context partials)  (64 x 1024)
// ---------------------------------------------------------------------------
__global__ void x_kernel(const int* __restrict__ ids, const float* __restrict__ emb,
                         const float* __restrict__ ctxpart, float* __restrict__ x) {
    int idx = blockIdx.x * 256 + threadIdx.x;
    int b = idx >> 10, k = idx & 1023;
    if (k < 512) {
        x[idx] = emb[(size_t)ids[b] * 512 + k];
    } else {
        int kk = k - 512;
        float s = 0.f;
#pragma unroll
        for (int i = 0; i < 16; ++i) s += ctxpart[((size_t)i * 64 + b) * 512 + kk];
        x[idx] = s;
    }
}

// ---------------------------------------------------------------------------
// GRU cell elementwise -> o (f32, d_out) and h (bf16, ws)
// ---------------------------------------------------------------------------
__global__ void gru_kernel(const float* __restrict__ gi, const float* __restrict__ gh,
                           const float* __restrict__ bih, const float* __restrict__ bhh,
                           const float* __restrict__ hidden, float* __restrict__ o_out,
                           short* __restrict__ hbf) {
    int idx = blockIdx.x * 256 + threadIdx.x;
    int b = idx >> 10, h = idx & 1023;
    const float* gib = gi + b * 3072;
    const float* ghb = gh + b * 3072;
    float ir = gib[h] + bih[h],               hr = ghb[h] + bhh[h];
    float iz = gib[1024 + h] + bih[1024 + h], hz = ghb[1024 + h] + bhh[1024 + h];
    float in = gib[2048 + h] + bih[2048 + h], hn = ghb[2048 + h] + bhh[2048 + h];
    float r = 1.0f / (1.0f + __expf(-(ir + hr)));
    float z = 1.0f / (1.0f + __expf(-(iz + hz)));
    float nn = tanhf(in + r * hn);
    float hq = hidden[idx];
    float hnew = (1.0f - z) * nn + z * hq;
    o_out[idx] = hnew;
    hbf[idx] = f2bf(hnew);
}

// ---------------------------------------------------------------------------
// logits = h(64x1024) @ W_out^T + b_out  (MFMA, B converted inline)
// ---------------------------------------------------------------------------
__global__ __launch_bounds__(256) void logits_kernel(const short* __restrict__ hbf,
                                                     const float* __restrict__ Wout,
                                                     const float* __restrict__ bout,
                                                     float* __restrict__ logits) {
    int tid = threadIdx.x, lane = tid & 63, wv = tid >> 6;
    int q = lane >> 4, c = lane & 15;
    int v = blockIdx.x * 64 + wv * 16 + c;
    int vc = v < VOCAB ? v : (VOCAB - 1);
    const float* wrow = Wout + (size_t)vc * 1024;
    f32x4 acc[4];
#pragma unroll
    for (int mi = 0; mi < 4; ++mi) acc[mi] = (f32x4){0.f, 0.f, 0.f, 0.f};
#pragma unroll 4
    for (int ks = 0; ks < 32; ++ks) {
        int k0 = ks * 32 + q * 8;
        float4 w0 = *(const float4*)(wrow + k0);
        float4 w1 = *(const float4*)(wrow + k0 + 4);
        bf16x8 bfr;
        bfr[0] = f2bf(w0.x); bfr[1] = f2bf(w0.y); bfr[2] = f2bf(w0.z); bfr[3] = f2bf(w0.w);
        bfr[4] = f2bf(w1.x); bfr[5] = f2bf(w1.y); bfr[6] = f2bf(w1.z); bfr[7] = f2bf(w1.w);
#pragma unroll
        for (int mi = 0; mi < 4; ++mi) {
            bf16x8 af = *(const bf16x8*)(hbf + (size_t)(mi * 16 + c) * 1024 + k0);
            acc[mi] = __builtin_amdgcn_mfma_f32_16x16x32_bf16(af, bfr, acc[mi], 0, 0, 0);
        }
    }
    if (v < VOCAB) {
        float bo = bout[v];
#pragma unroll
        for (int mi = 0; mi < 4; ++mi)
#pragma unroll
            for (int rg = 0; rg < 4; ++rg) {
                int row = mi * 16 + q * 4 + rg;
                logits[(size_t)row * VOCAB + v] = acc[mi][rg] + bo;
            }
    }
}

// ---------------------------------------------------------------------------
// log_softmax split: 256 blocks (64 rows x 4 chunks) instead of 64 blocks.
// Pass 1: per-chunk max + sum(exp(x-max)) -> lsm[b][ch] = (m,s).
// Pass 2: combine 4 partials (tiny), subtract lse over own chunk.
// Removes the 64-block occupancy ceiling (old kernel used 1/4 of CUs).
// ---------------------------------------------------------------------------
#define LSM_CHUNK 12565  // ceil(50257/4)

__global__ __launch_bounds__(256) void lsm_partial_kernel(const float* __restrict__ logp,
                                                          float* __restrict__ lsm) {
    __shared__ float red[8];
    int blk = blockIdx.x;
    int b = blk >> 2, ch = blk & 3;
    const float* row = logp + (size_t)b * VOCAB;
    int i0 = ch * LSM_CHUNK;
    int i1 = i0 + LSM_CHUNK; if (i1 > VOCAB) i1 = VOCAB;
    int tid = threadIdx.x;
    float vmax = -1e30f;
    for (int i = i0 + tid; i < i1; i += 256) vmax = fmaxf(vmax, row[i]);
#pragma unroll
    for (int m = 32; m; m >>= 1) vmax = fmaxf(vmax, __shfl_xor(vmax, m));
    if ((tid & 63) == 0) red[tid >> 6] = vmax;
    __syncthreads();
    vmax = fmaxf(fmaxf(red[0], red[1]), fmaxf(red[2], red[3]));
    float sum = 0.f;
    for (int i = i0 + tid; i < i1; i += 256) sum += __expf(row[i] - vmax);
#pragma unroll
    for (int m = 32; m; m >>= 1) sum += __shfl_xor(sum, m);
    __syncthreads();
    if ((tid & 63) == 0) red[4 + (tid >> 6)] = sum;
    __syncthreads();
    if (tid == 0) {
        lsm[(b << 3) + (ch << 1)] = vmax;
        lsm[(b << 3) + (ch << 1) + 1] = red[4] + red[5] + red[6] + red[7];
    }
}

__global__ __launch_bounds__(256) void lsm_apply_kernel(float* __restrict__ logp,
                                                        const float* __restrict__ lsm) {
    int blk = blockIdx.x;
    int b = blk >> 2, ch = blk & 3;
    const float* p = lsm + (b << 3);
    float m0 = fmaxf(fmaxf(p[0], p[2]), fmaxf(p[4], p[6]));
    float s = p[1] * __expf(p[0] - m0) + p[3] * __expf(p[2] - m0) +
              p[5] * __expf(p[4] - m0) + p[7] * __expf(p[6] - m0);
    float lse = m0 + logf(s);
    float* row = logp + (size_t)b * VOCAB;
    int i0 = ch * LSM_CHUNK;
    int i1 = i0 + LSM_CHUNK; if (i1 > VOCAB) i1 = VOCAB;
    for (int i = i0 + threadIdx.x; i < i1; i += 256) row[i] -= lse;
}

// ---------------------------------------------------------------------------
extern "C" void kernel_launch(void* const* d_in, const int* in_sizes, int n_in,
                              void* d_out, int out_size, void* d_ws, size_t ws_size,
                              hipStream_t stream) {
    const int* ids      = (const int*)d_in[0];
    const float* hidden = (const float*)d_in[1];
    const float* ann    = (const float*)d_in[2];
    const float* embT   = (const float*)d_in[3];
    const float* Wk     = (const float*)d_in[4];
    const float* Wq     = (const float*)d_in[5];
    const float* bk     = (const float*)d_in[6];
    const float* vat    = (const float*)d_in[7];
    const float* Wih    = (const float*)d_in[8];
    const float* Whh    = (const float*)d_in[9];
    const float* bih    = (const float*)d_in[10];
    const float* bhh    = (const float*)d_in[11];
    const float* Wout   = (const float*)d_in[12];
    const float* bout   = (const float*)d_in[13];

    float* out   = (float*)d_out;
    float* logp  = out;                         // 64*50257 (logits in-place)
    float* o_out = out + (size_t)BATCH * VOCAB; // 64*1024
    float* a_out = o_out + BATCH * HID;         // 64*2048

    // ws layout (floats). scores2 (262144) and ctxpart (524288) overlay:
    // softmax consumes scores2 before context writes ctxpart.
    float* shared0 = (float*)d_ws;
    float* scores2 = shared0;
    float* ctxpart = shared0;
    float* qc      = shared0 + 524288;          // 65536
    float* gh      = qc + 65536;                // 196608
    float* gi      = gh + 196608;               // 196608
    float* x       = gi + 196608;               // 65536
    short* wkT     = (short*)(x + 65536);       // 524288 shorts
    short* hbf     = wkT + 524288;              // 65536 shorts
    // lsm partials (512 floats) overlay qc: qc is dead after scores_kernel,
    // lsm is produced/consumed at the very end of the launch. Zero ws growth.
    float* lsm     = qc;

    // zero atomic-accumulated regions qc|gh|gi (contiguous, 458752 floats)
    hipMemsetAsync(qc, 0, (size_t)458752 * sizeof(float), stream);

    wkt_kernel<<<dim3(16, 32), dim3(32, 8), 0, stream>>>(Wk, wkT);
    sgemm64<0><<<dim3(16, 8), 256, 0, stream>>>(hidden, Wq, qc, 1024, 1024);
    sgemm64<1><<<dim3(48, 8), 256, 0, stream>>>(hidden, Whh, gh, 3072, 1024);
    scores_kernel<<<2048, 512, 0, stream>>>(ann, wkT, qc, bk, vat, scores2);
    softmax_kernel<<<64, 256, 0, stream>>>(scores2, a_out);
    context_kernel<<<dim3(16, 64), 256, 0, stream>>>(a_out, ann, ctxpart);
    x_kernel<<<256, 256, 0, stream>>>(ids, embT, ctxpart, x);
    sgemm64<1><<<dim3(48, 8), 256, 0, stream>>>(x, Wih, gi, 3072, 1024);
    gru_kernel<<<256, 256, 0, stream>>>(gi, gh, bih, bhh, hidden, o_out, hbf);
    logits_kernel<<<(VOCAB + 63) / 64, 256, 0, stream>>>(hbf, Wout, bout, logp);
    lsm_partial_kernel<<<256, 256, 0, stream>>>(logp, lsm);
    lsm_apply_kernel<<<256, 256, 0, stream>>>(logp, lsm);
}

// Round 9
// 900.368 us; speedup vs baseline: 1.0305x; 1.0081x over previous
//
#include <hip/hip_runtime.h>
#include <hip/hip_bf16.h>
#include <cstddef>

#define BATCH 64
#define NK    2048
#define HID   1024
#define EMB   512
#define KEY   512
#define VOCAB 50257

typedef __attribute__((ext_vector_type(8))) short bf16x8;
typedef __attribute__((ext_vector_type(4))) short bf16x4;
typedef __attribute__((ext_vector_type(4))) float f32x4;

__device__ __forceinline__ short f2bf(float f) {
    unsigned u = __builtin_bit_cast(unsigned, f);
    unsigned r = (u + 0x7FFFu + ((u >> 16) & 1u)) >> 16;
    return (short)r;
}

// hardware packed f32->bf16 (RNE, same rounding as f2bf): 1 VALU op for 2 elems
__device__ __forceinline__ unsigned cvtpk(float lo, float hi) {
    unsigned r;
    asm("v_cvt_pk_bf16_f32 %0, %1, %2" : "=v"(r) : "v"(lo), "v"(hi));
    return r;
}

#define GLOAD_LDS16(g, l)                                                  \
    __builtin_amdgcn_global_load_lds(                                      \
        (const __attribute__((address_space(1))) void*)(g),                \
        (__attribute__((address_space(3))) void*)(l), 16, 0, 0)

// ---------------------------------------------------------------------------
// Wk transpose piece (device fn): Wk (512 x 1024) f32 -> wkT (1024 x 512) bf16
// flat 256-thread block; tx = tid&31, ty = tid>>5 (orig (32,8) mapping)
// ---------------------------------------------------------------------------
__device__ __forceinline__ void wkt_dev(const float* __restrict__ Wk,
                                        short* __restrict__ wkT,
                                        int bx, int by, float* smem) {
    float (*t)[33] = (float(*)[33])smem;
    int k0 = bx << 5, n0 = by << 5;
    int tx = threadIdx.x & 31, ty = threadIdx.x >> 5;
#pragma unroll
    for (int i = 0; i < 4; ++i)
        t[ty + i * 8][tx] = Wk[(size_t)(k0 + ty + i * 8) * 1024 + n0 + tx];
    __syncthreads();
#pragma unroll
    for (int i = 0; i < 4; ++i)
        wkT[(size_t)(n0 + ty + i * 8) * 512 + k0 + tx] = f2bf(t[tx][ty + i * 8]);
}

// ---------------------------------------------------------------------------
// Small fp32 GEMM body: C(64 x N) += A(64 x K=1024) * B
// B either [K][N] (TB=0) or [N][K] (TB=1). k-split by 'by'. atomic accum.
// ---------------------------------------------------------------------------
template <int TB>
__device__ __forceinline__ void sgemm_dev(const float* __restrict__ A,
                                          const float* __restrict__ B,
                                          float* __restrict__ C, int N, int K,
                                          int bx, int by, float* smem) {
    float (*As2)[68] = (float(*)[68])smem;
    float (*Bs2)[68] = (float(*)[68])(smem + 32 * 68);
    int tid = threadIdx.x;
    int n0 = bx << 6;
    int kb = by << 7; // K/8 = 128 per split
    int tn = (tid & 15) << 2, tm = (tid >> 4) << 2;
    float acc[4][4] = {};
    for (int kc = 0; kc < 128; kc += 32) {
        int kk = kb + kc;
#pragma unroll
        for (int i = 0; i < 8; ++i) {
            int idx = i * 256 + tid;
            int ml = idx >> 5, kl = idx & 31;
            As2[kl][ml] = A[(size_t)ml * K + kk + kl];
        }
        if (TB) {
#pragma unroll
            for (int i = 0; i < 8; ++i) {
                int idx = i * 256 + tid;
                int nl = idx >> 5, kl = idx & 31;
                Bs2[kl][nl] = B[(size_t)(n0 + nl) * K + kk + kl];
            }
        } else {
#pragma unroll
            for (int i = 0; i < 8; ++i) {
                int idx = i * 256 + tid;
                int kl = idx >> 6, nl = idx & 63;
                Bs2[kl][nl] = B[(size_t)(kk + kl) * N + n0 + nl];
            }
        }
        __syncthreads();
#pragma unroll
        for (int k = 0; k < 32; ++k) {
            float a0 = As2[k][tm], a1 = As2[k][tm + 1], a2 = As2[k][tm + 2], a3 = As2[k][tm + 3];
            float b0 = Bs2[k][tn], b1 = Bs2[k][tn + 1], b2 = Bs2[k][tn + 2], b3 = Bs2[k][tn + 3];
            acc[0][0] += a0 * b0; acc[0][1] += a0 * b1; acc[0][2] += a0 * b2; acc[0][3] += a0 * b3;
            acc[1][0] += a1 * b0; acc[1][1] += a1 * b1; acc[1][2] += a1 * b2; acc[1][3] += a1 * b3;
            acc[2][0] += a2 * b0; acc[2][1] += a2 * b1; acc[2][2] += a2 * b2; acc[2][3] += a2 * b3;
            acc[3][0] += a3 * b0; acc[3][1] += a3 * b1; acc[3][2] += a3 * b2; acc[3][3] += a3 * b3;
        }
        __syncthreads();
    }
#pragma unroll
    for (int i = 0; i < 4; ++i)
#pragma unroll
        for (int j = 0; j < 4; ++j)
            atomicAdd(&C[(size_t)(tm + i) * N + n0 + tn + j], acc[i][j]);
}

template <int TB>
__global__ __launch_bounds__(256) void sgemm64(const float* __restrict__ A,
                                               const float* __restrict__ B,
                                               float* __restrict__ C, int N, int K) {
    __shared__ float smem[2 * 32 * 68];
    sgemm_dev<TB>(A, B, C, N, K, blockIdx.x, blockIdx.y, smem);
}

// ---------------------------------------------------------------------------
// prep: fuse 3 independent pre-scores kernels into one launch.
// blocks 0..511   -> wkt transpose (orig grid 16x32)
// blocks 512..639 -> sgemm<0> Wq  (orig grid 16x8)
// blocks 640..1023-> sgemm<1> Whh (orig grid 48x8)
// Branch is block-uniform; LDS unioned (sgemm's 17.4 KB dominates).
// ---------------------------------------------------------------------------
__global__ __launch_bounds__(256) void prep_kernel(const float* __restrict__ Wk,
                                                   short* __restrict__ wkT,
                                                   const float* __restrict__ hidden,
                                                   const float* __restrict__ Wq,
                                                   const float* __restrict__ Whh,
                                                   float* __restrict__ qc,
                                                   float* __restrict__ gh) {
    __shared__ float smem[2 * 32 * 68];
    int blk = blockIdx.x;
    if (blk < 512) {
        wkt_dev(Wk, wkT, blk & 15, blk >> 4, smem);
    } else if (blk < 640) {
        int i = blk - 512;
        sgemm_dev<0>(hidden, Wq, qc, 1024, 1024, i & 15, i >> 4, smem);
    } else {
        int i = blk - 640;
        sgemm_dev<1>(hidden, Whh, gh, 3072, 1024, i % 48, i / 48, smem);
    }
}

// ---------------------------------------------------------------------------
// scores v3 + cvt_pk A-pack (replaces ~32 VALU of manual f2bf twiddle with
// 4 v_cvt_pk_bf16_f32 per thread per iter; RNE either way so bits match).
// Double-buffered single-barrier pipeline, proven 271 us structure.
// ---------------------------------------------------------------------------
__global__ __launch_bounds__(512, 4) void scores_kernel(const float* __restrict__ ann,
                                                        const short* __restrict__ wkT,
                                                        const float* __restrict__ qc,
                                                        const float* __restrict__ bk,
                                                        const float* __restrict__ vat,
                                                        float* __restrict__ scores2) {
    __shared__ __align__(16) short As[2 * 128 * 32];
    __shared__ __align__(16) short Bs[2 * 256 * 32];
    __shared__ float red[128][4];

    int bx = blockIdx.x;
    int rb = ((bx >> 4) << 3) | (bx & 7);
    int hs = (bx >> 3) & 1;
    int row0 = rb << 7;
    int b = row0 >> 11;
    int tid = threadIdx.x, lane = tid & 63, wv = tid >> 6;
    int wm = wv & 1, wn = wv >> 1;       // 2 m-waves x 4 n-waves
    int q = lane >> 4, c = lane & 15;

    // staging lane roles
    int sm = tid >> 2;                    // A row 0..127 / B row-in-128 chunk
    int sq = tid & 3;                     // logical k-quarter (A) / phys slot (B)
    int sxor = (tid >> 3) & 3;            // (row>>1)&3 for both A and B lanes
    int aphys = sq ^ sxor;                // A: physical slot
    int bqlog = sq ^ sxor;                // B: logical quarter for phys slot sq
    int swz = (q ^ ((c >> 1) & 3)) << 3;  // frag-read swizzled short-offset

    const float* qcb = qc + b * 1024;
    const float* abase = ann + (size_t)(row0 + sm) * 512 + sq * 8;
    const short* bbase = wkT + (size_t)(hs * 512 + sm) * 512 + bqlog * 8;

    float pscore[4][4] = {};
    f32x4 acc[4][4];
#pragma unroll
    for (int mi = 0; mi < 4; ++mi)
#pragma unroll
        for (int ni = 0; ni < 4; ++ni)
            acc[mi][ni] = (f32x4){0.f, 0.f, 0.f, 0.f};

    // ---- prologue: tile0 into buf0, A-regs for tile1 in flight ----
    float4 pa0 = *(const float4*)abase;
    float4 pa1 = *(const float4*)(abase + 4);
    GLOAD_LDS16(bbase, Bs + (wv << 9));
    GLOAD_LDS16(bbase + 128 * 512, Bs + 4096 + (wv << 9));
    {
        uint4 ap;
        ap.x = cvtpk(pa0.x, pa0.y); ap.y = cvtpk(pa0.z, pa0.w);
        ap.z = cvtpk(pa1.x, pa1.y); ap.w = cvtpk(pa1.z, pa1.w);
        *(uint4*)(As + sm * 32 + aphys * 8) = ap;
    }
    pa0 = *(const float4*)(abase + 32);
    pa1 = *(const float4*)(abase + 36);
    __syncthreads();

    // ---- main pipeline: t = nc*16 + ks ----
#pragma unroll 2
    for (int t = 0; t < 32; ++t) {
        short* Asc = As + (t & 1) * 4096;
        short* Bsc = Bs + ((t & 1) << 13);
        short* Asn = As + ((t & 1) ^ 1) * 4096;
        short* Bsn = Bs + (((t & 1) ^ 1) << 13);
        if (t < 31) {
            int t1 = t + 1;
            const short* bs = bbase + (size_t)((t1 >> 4) * (256 * 512)) + ((t1 & 15) << 5);
            GLOAD_LDS16(bs, Bsn + (wv << 9));
            GLOAD_LDS16(bs + 128 * 512, Bsn + 4096 + (wv << 9));
            uint4 ap;
            ap.x = cvtpk(pa0.x, pa0.y); ap.y = cvtpk(pa0.z, pa0.w);
            ap.z = cvtpk(pa1.x, pa1.y); ap.w = cvtpk(pa1.z, pa1.w);
            *(uint4*)(Asn + sm * 32 + aphys * 8) = ap;
        }
        if (t < 30) {
            const float* as = abase + (((t + 2) & 15) << 5);
            pa0 = *(const float4*)as;
            pa1 = *(const float4*)(as + 4);
        }
        // ---- fragments + MFMA from front buffer ----
        bf16x8 af[4];
#pragma unroll
        for (int mi = 0; mi < 4; ++mi)
            af[mi] = *(const bf16x8*)(Asc + (wm * 64 + mi * 16 + c) * 32 + swz);
#pragma unroll
        for (int ni = 0; ni < 4; ++ni) {
            bf16x8 bfr = *(const bf16x8*)(Bsc + (wn * 64 + ni * 16 + c) * 32 + swz);
#pragma unroll
            for (int mi = 0; mi < 4; ++mi)
                acc[mi][ni] = __builtin_amdgcn_mfma_f32_16x16x32_bf16(af[mi], bfr, acc[mi][ni], 0, 0, 0);
        }
        // ---- epilogue per 256-h chunk: tanh(S+qc+bk)*v, accumulate ----
        if ((t & 15) == 15) {
            int hbase = hs * 512 + (t >> 4) * 256 + wn * 64;
#pragma unroll
            for (int ni = 0; ni < 4; ++ni) {
                int h = hbase + ni * 16 + c;
                float qv = qcb[h] + bk[h];
                float vv = vat[h];
#pragma unroll
                for (int mi = 0; mi < 4; ++mi) {
#pragma unroll
                    for (int rg = 0; rg < 4; ++rg) {
                        float xv = acc[mi][ni][rg] + qv;
                        float e = __expf(2.0f * xv);
                        pscore[mi][rg] += (1.0f - 2.0f / (e + 1.0f)) * vv;
                        acc[mi][ni][rg] = 0.f;
                    }
                }
            }
        }
        __syncthreads();
    }

    // ---- cross-lane + cross-wave reduction, direct store (no atomics) ----
#pragma unroll
    for (int mi = 0; mi < 4; ++mi)
#pragma unroll
        for (int rg = 0; rg < 4; ++rg) {
            float p = pscore[mi][rg];
            p += __shfl_xor(p, 1, 16);
            p += __shfl_xor(p, 2, 16);
            p += __shfl_xor(p, 4, 16);
            p += __shfl_xor(p, 8, 16);
            if (c == 0) red[wm * 64 + mi * 16 + q * 4 + rg][wn] = p;
        }
    __syncthreads();
    if (tid < 128)
        scores2[(size_t)hs * 131072 + row0 + tid] =
            red[tid][0] + red[tid][1] + red[tid][2] + red[tid][3];
}

// ---------------------------------------------------------------------------
// softmax over NK=2048 per batch row, summing the two h-half planes
// ---------------------------------------------------------------------------
__global__ __launch_bounds__(256) void softmax_kernel(const float* __restrict__ scores2,
                                                      float* __restrict__ a_out) {
    __shared__ float red[4];
    int b = blockIdx.x, tid = threadIdx.x;
    const float* s0 = scores2 + b * 2048;
    const float* s1 = s0 + 131072;
    float loc[8];
    float vmax = -1e30f;
#pragma unroll
    for (int i = 0; i < 8; ++i) {
        loc[i] = s0[tid + i * 256] + s1[tid + i * 256];
        vmax = fmaxf(vmax, loc[i]);
    }
#pragma unroll
    for (int m = 32; m; m >>= 1) vmax = fmaxf(vmax, __shfl_xor(vmax, m));
    if ((tid & 63) == 0) red[tid >> 6] = vmax;
    __syncthreads();
    vmax = fmaxf(fmaxf(red[0], red[1]), fmaxf(red[2], red[3]));
    float sum = 0.f;
#pragma unroll
    for (int i = 0; i < 8; ++i) { loc[i] = __expf(loc[i] - vmax); sum += loc[i]; }
#pragma unroll
    for (int m = 32; m; m >>= 1) sum += __shfl_xor(sum, m);
    __syncthreads();
    if ((tid & 63) == 0) red[tid >> 6] = sum;
    __syncthreads();
    sum = red[0] + red[1] + red[2] + red[3];
    float inv = 1.0f / sum;
#pragma unroll
    for (int i = 0; i < 8; ++i) a_out[b * 2048 + tid + i * 256] = loc[i] * inv;
}

// ---------------------------------------------------------------------------
// context partials: part[nchunk][b][k] = sum over 128 n (no atomics)
// ---------------------------------------------------------------------------
__global__ __launch_bounds__(256) void context_kernel(const float* __restrict__ a_out,
                                                      const float* __restrict__ ann,
                                                      float* __restrict__ ctxpart) {
    int b = blockIdx.y, nch = blockIdx.x, n0 = nch << 7;
    int k = threadIdx.x << 1;
    const float* base = ann + ((size_t)b * 2048 + n0) * 512 + k;
    const float* av = a_out + b * 2048 + n0;
    float ax = 0.f, ay = 0.f;
#pragma unroll 4
    for (int n = 0; n < 128; ++n) {
        float w = av[n];
        float2 v = *(const float2*)(base + (size_t)n * 512);
        ax += w * v.x;
        ay += w * v.y;
    }
    float* dst = ctxpart + ((size_t)nch * 64 + b) * 512 + k;
    dst[0] = ax;
    dst[1] = ay;
}

// ---------------------------------------------------------------------------
// x = concat(emb_table[ids], sum of 16 context partials)  (64 x 1024)
// ---------------------------------------------------------------------------
__global__ void x_kernel(const int* __restrict__ ids, const float* __restrict__ emb,
                         const float* __restrict__ ctxpart, float* __restrict__ x) {
    int idx = blockIdx.x * 256 + threadIdx.x;
    int b = idx >> 10, k = idx & 1023;
    if (k < 512) {
        x[idx] = emb[(size_t)ids[b] * 512 + k];
    } else {
        int kk = k - 512;
        float s = 0.f;
#pragma unroll
        for (int i = 0; i < 16; ++i) s += ctxpart[((size_t)i * 64 + b) * 512 + kk];
        x[idx] = s;
    }
}

// ---------------------------------------------------------------------------
// GRU cell elementwise -> o (f32, d_out) and h (bf16, ws)
// ---------------------------------------------------------------------------
__global__ void gru_kernel(const float* __restrict__ gi, const float* __restrict__ gh,
                           const float* __restrict__ bih, const float* __restrict__ bhh,
                           const float* __restrict__ hidden, float* __restrict__ o_out,
                           short* __restrict__ hbf) {
    int idx = blockIdx.x * 256 + threadIdx.x;
    int b = idx >> 10, h = idx & 1023;
    const float* gib = gi + b * 3072;
    const float* ghb = gh + b * 3072;
    float ir = gib[h] + bih[h],               hr = ghb[h] + bhh[h];
    float iz = gib[1024 + h] + bih[1024 + h], hz = ghb[1024 + h] + bhh[1024 + h];
    float in = gib[2048 + h] + bih[2048 + h], hn = ghb[2048 + h] + bhh[2048 + h];
    float r = 1.0f / (1.0f + __expf(-(ir + hr)));
    float z = 1.0f / (1.0f + __expf(-(iz + hz)));
    float nn = tanhf(in + r * hn);
    float hq = hidden[idx];
    float hnew = (1.0f - z) * nn + z * hq;
    o_out[idx] = hnew;
    hbf[idx] = f2bf(hnew);
}

// ---------------------------------------------------------------------------
// logits = h(64x1024) @ W_out^T + b_out  (MFMA, B converted inline via cvt_pk)
// ---------------------------------------------------------------------------
__global__ __launch_bounds__(256) void logits_kernel(const short* __restrict__ hbf,
                                                     const float* __restrict__ Wout,
                                                     const float* __restrict__ bout,
                                                     float* __restrict__ logits) {
    int tid = threadIdx.x, lane = tid & 63, wv = tid >> 6;
    int q = lane >> 4, c = lane & 15;
    int v = blockIdx.x * 64 + wv * 16 + c;
    int vc = v < VOCAB ? v : (VOCAB - 1);
    const float* wrow = Wout + (size_t)vc * 1024;
    f32x4 acc[4];
#pragma unroll
    for (int mi = 0; mi < 4; ++mi) acc[mi] = (f32x4){0.f, 0.f, 0.f, 0.f};
#pragma unroll 4
    for (int ks = 0; ks < 32; ++ks) {
        int k0 = ks * 32 + q * 8;
        float4 w0 = *(const float4*)(wrow + k0);
        float4 w1 = *(const float4*)(wrow + k0 + 4);
        uint4 wp;
        wp.x = cvtpk(w0.x, w0.y); wp.y = cvtpk(w0.z, w0.w);
        wp.z = cvtpk(w1.x, w1.y); wp.w = cvtpk(w1.z, w1.w);
        bf16x8 bfr = __builtin_bit_cast(bf16x8, wp);
#pragma unroll
        for (int mi = 0; mi < 4; ++mi) {
            bf16x8 af = *(const bf16x8*)(hbf + (size_t)(mi * 16 + c) * 1024 + k0);
            acc[mi] = __builtin_amdgcn_mfma_f32_16x16x32_bf16(af, bfr, acc[mi], 0, 0, 0);
        }
    }
    if (v < VOCAB) {
        float bo = bout[v];
#pragma unroll
        for (int mi = 0; mi < 4; ++mi)
#pragma unroll
            for (int rg = 0; rg < 4; ++rg) {
                int row = mi * 16 + q * 4 + rg;
                logits[(size_t)row * VOCAB + v] = acc[mi][rg] + bo;
            }
    }
}

// ---------------------------------------------------------------------------
// log_softmax split: 256 blocks (64 rows x 4 chunks).
// ---------------------------------------------------------------------------
#define LSM_CHUNK 12565  // ceil(50257/4)

__global__ __launch_bounds__(256) void lsm_partial_kernel(const float* __restrict__ logp,
                                                          float* __restrict__ lsm) {
    __shared__ float red[8];
    int blk = blockIdx.x;
    int b = blk >> 2, ch = blk & 3;
    const float* row = logp + (size_t)b * VOCAB;
    int i0 = ch * LSM_CHUNK;
    int i1 = i0 + LSM_CHUNK; if (i1 > VOCAB) i1 = VOCAB;
    int tid = threadIdx.x;
    float vmax = -1e30f;
    for (int i = i0 + tid; i < i1; i += 256) vmax = fmaxf(vmax, row[i]);
#pragma unroll
    for (int m = 32; m; m >>= 1) vmax = fmaxf(vmax, __shfl_xor(vmax, m));
    if ((tid & 63) == 0) red[tid >> 6] = vmax;
    __syncthreads();
    vmax = fmaxf(fmaxf(red[0], red[1]), fmaxf(red[2], red[3]));
    float sum = 0.f;
    for (int i = i0 + tid; i < i1; i += 256) sum += __expf(row[i] - vmax);
#pragma unroll
    for (int m = 32; m; m >>= 1) sum += __shfl_xor(sum, m);
    __syncthreads();
    if ((tid & 63) == 0) red[4 + (tid >> 6)] = sum;
    __syncthreads();
    if (tid == 0) {
        lsm[(b << 3) + (ch << 1)] = vmax;
        lsm[(b << 3) + (ch << 1) + 1] = red[4] + red[5] + red[6] + red[7];
    }
}

__global__ __launch_bounds__(256) void lsm_apply_kernel(float* __restrict__ logp,
                                                        const float* __restrict__ lsm) {
    int blk = blockIdx.x;
    int b = blk >> 2, ch = blk & 3;
    const float* p = lsm + (b << 3);
    float m0 = fmaxf(fmaxf(p[0], p[2]), fmaxf(p[4], p[6]));
    float s = p[1] * __expf(p[0] - m0) + p[3] * __expf(p[2] - m0) +
              p[5] * __expf(p[4] - m0) + p[7] * __expf(p[6] - m0);
    float lse = m0 + logf(s);
    float* row = logp + (size_t)b * VOCAB;
    int i0 = ch * LSM_CHUNK;
    int i1 = i0 + LSM_CHUNK; if (i1 > VOCAB) i1 = VOCAB;
    for (int i = i0 + threadIdx.x; i < i1; i += 256) row[i] -= lse;
}

// ---------------------------------------------------------------------------
extern "C" void kernel_launch(void* const* d_in, const int* in_sizes, int n_in,
                              void* d_out, int out_size, void* d_ws, size_t ws_size,
                              hipStream_t stream) {
    const int* ids      = (const int*)d_in[0];
    const float* hidden = (const float*)d_in[1];
    const float* ann    = (const float*)d_in[2];
    const float* embT   = (const float*)d_in[3];
    const float* Wk     = (const float*)d_in[4];
    const float* Wq     = (const float*)d_in[5];
    const float* bk     = (const float*)d_in[6];
    const float* vat    = (const float*)d_in[7];
    const float* Wih    = (const float*)d_in[8];
    const float* Whh    = (const float*)d_in[9];
    const float* bih    = (const float*)d_in[10];
    const float* bhh    = (const float*)d_in[11];
    const float* Wout   = (const float*)d_in[12];
    const float* bout   = (const float*)d_in[13];

    float* out   = (float*)d_out;
    float* logp  = out;                         // 64*50257 (logits in-place)
    float* o_out = out + (size_t)BATCH * VOCAB; // 64*1024
    float* a_out = o_out + BATCH * HID;         // 64*2048

    // ws layout (floats). scores2 (262144) and ctxpart (524288) overlay:
    // softmax consumes scores2 before context writes ctxpart.
    float* shared0 = (float*)d_ws;
    float* scores2 = shared0;
    float* ctxpart = shared0;
    float* qc      = shared0 + 524288;          // 65536
    float* gh      = qc + 65536;                // 196608
    float* gi      = gh + 196608;               // 196608
    float* x       = gi + 196608;               // 65536
    short* wkT     = (short*)(x + 65536);       // 524288 shorts
    short* hbf     = wkT + 524288;              // 65536 shorts
    // lsm partials (512 floats) overlay qc (dead after scores; reborn at end)
    float* lsm     = qc;

    // zero atomic-accumulated regions qc|gh|gi (contiguous, 458752 floats)
    hipMemsetAsync(qc, 0, (size_t)458752 * sizeof(float), stream);

    prep_kernel<<<1024, 256, 0, stream>>>(Wk, wkT, hidden, Wq, Whh, qc, gh);
    scores_kernel<<<2048, 512, 0, stream>>>(ann, wkT, qc, bk, vat, scores2);
    softmax_kernel<<<64, 256, 0, stream>>>(scores2, a_out);
    context_kernel<<<dim3(16, 64), 256, 0, stream>>>(a_out, ann, ctxpart);
    x_kernel<<<256, 256, 0, stream>>>(ids, embT, ctxpart, x);
    sgemm64<1><<<dim3(48, 8), 256, 0, stream>>>(x, Wih, gi, 3072, 1024);
    gru_kernel<<<256, 256, 0, stream>>>(gi, gh, bih, bhh, hidden, o_out, hbf);
    logits_kernel<<<(VOCAB + 63) / 64, 256, 0, stream>>>(hbf, Wout, bout, logp);
    lsm_partial_kernel<<<256, 256, 0, stream>>>(logp, lsm);
    lsm_apply_kernel<<<256, 256, 0, stream>>>(logp, lsm);
}